// Round 10
// baseline (138.832 us; speedup 1.0000x reference)
//
#include <hip/hip_runtime.h>
#include <hip/hip_cooperative_groups.h>
#include <math.h>

namespace cg = cooperative_groups;

#define NN 512
#define DD 256

#define FMA4(P, S, V) \
  P.x = fmaf(S, (V).x, P.x); P.y = fmaf(S, (V).y, P.y); \
  P.z = fmaf(S, (V).z, P.z); P.w = fmaf(S, (V).w, P.w);

__device__ __forceinline__ double wred_sum(double v){
  #pragma unroll
  for (int o = 32; o > 0; o >>= 1) v += __shfl_down(v, o);
  return v;
}

__device__ __forceinline__ double artanh_clip(double x){
  const double lim = 1.0 - 1e-5;           // BALL_EPS
  if (x >  lim) x =  lim;
  if (x < -lim) x = -lim;
  return 0.5 * log((1.0 + x) / (1.0 - x));
}

// ---------- fused body (R4-proven 512-thread version, verbatim math) ----------
// xs (this block's 2 Wh rows) is preloaded in LDS by the previous stage.
// Row-major Wh is never touched; tail leaves next-layer rows in xs.
template<bool LAST>
__device__ void fused_body(int b, int tid,
    const float* __restrict__ WhT, const double* __restrict__ r2,
    const int* __restrict__ A, const float* __restrict__ H,
    const float* __restrict__ WT2,
    float* __restrict__ HnOut, float* __restrict__ WhTn, double* __restrict__ r2n,
    float* xs, float (*a_s)[NN], float4* parts, double* ssum,
    float (*hn_s)[DD], double* hnorm2)
{
  int i0 = 2 * b;

  // ---- Phase A: Gram partials (coalesced WhT stream) ----
  {
    int ks = tid >> 7, jq = tid & 127;  // 4 k-segs of 64 dims, column-quad
    const float4* WT4 = (const float4*)WhT;        // [k*128 + jq]
    const float4* x04 = (const float4*)xs;
    const float4* x14 = (const float4*)(xs + DD);
    float4 p0 = {0,0,0,0}, p1 = {0,0,0,0};
    int kq0 = ks * 16;
    #pragma unroll 4
    for (int kk = 0; kk < 16; kk++){
      float4 xa = x04[kq0 + kk], xb = x14[kq0 + kk];
      const float4* wp = WT4 + (kq0 + kk) * 512 + jq;
      float4 wa = wp[0], wb = wp[128], wc = wp[256], wd = wp[384];
      FMA4(p0, xa.x, wa) FMA4(p0, xa.y, wb) FMA4(p0, xa.z, wc) FMA4(p0, xa.w, wd)
      FMA4(p1, xb.x, wa) FMA4(p1, xb.y, wb) FMA4(p1, xb.z, wc) FMA4(p1, xb.w, wd)
    }
    parts[(ks * 128 + jq) * 2 + 0] = p0;
    parts[(ks * 128 + jq) * 2 + 1] = p1;
  }
  __syncthreads();

  // ---- Phase C prefetch: first 8 rows of this thread's j-segment ----
  int sgC = tid >> 6, qC = tid & 63;
  const float4* H4 = (const float4*)H;
  float4 hpre[8];
  #pragma unroll
  for (int jj = 0; jj < 8; jj++) hpre[jj] = H4[(sgC * 64 + jj) * 64 + qC];

  // ---- Phase B: scores + fixed-shift softmax ----
  int r = tid >> 8, j2 = tid & 255;     // waves 0-3: row i0, waves 4-7: row i1
  int i = i0 + r;
  double X2 = r2[i];
  const float* pf = (const float*)parts;          // ks stride = 1024 floats
  auto dsum = [&](int j) -> double {
    int base = (((j >> 2) * 2 + r) << 2) + (j & 3);
    return ((double)pf[base] + (double)pf[base + 1024])
         + ((double)pf[base + 2048] + (double)pf[base + 3072]);
  };
  double d0 = dsum(j2), d1 = dsum(j2 + 256);

  auto score = [&](double dot, double Y2, int jj) -> double {
    if (i == jj) return 0.0;            // exact: mobius_add(-x,x)=0
    double xy = -dot;
    double a  = 1.0 + 2.0 * xy + Y2;
    double bb = 1.0 - X2;
    double den = 1.0 + 2.0 * xy + X2 * Y2;
    if (den < 1e-15) den = 1e-15;
    double nn = a * a * X2 + 2.0 * a * bb * xy + bb * bb * Y2;
    if (nn < 0.0) nn = 0.0;
    double s = sqrt(nn);
    double smax = den * (1.0 - 1e-5);   // artanh arg clip at 1-1e-5
    if (s > smax) s = smax;
    double d = log((den + s) / (den - s)); // = 2*artanh(s/den), one div
    return d * d;
  };

  double Y0 = r2[j2], Y1 = r2[j2 + 256];
  int m0 = A[i * NN + j2], m1 = A[i * NN + j2 + 256];
  double e0 = 0.0, e1 = 0.0;
  if (m0) e0 = exp(score(d0, Y0, j2) - 150.0);       // scores in [0,150)
  if (m1) e1 = exp(score(d1, Y1, j2 + 256) - 150.0);

  double part = e0 + e1;
  part = wred_sum(part);
  int w = tid >> 6, lane = tid & 63;
  if (lane == 0) ssum[w] = part;
  __syncthreads();
  int base4 = r * 4;
  double sum = (ssum[base4] + ssum[base4 + 1]) + (ssum[base4 + 2] + ssum[base4 + 3]);
  double inv = 1.0 / sum;
  a_s[r][j2]       = m0 ? (float)(e0 * inv) : 0.f;
  a_s[r][j2 + 256] = m1 ? (float)(e1 * inv) : 0.f;
  __syncthreads();

  // ---- Phase C: att @ H, 8-way j-split; 8 prefetched + 56 streamed rows ----
  {
    float4 c0 = {0,0,0,0}, c1 = {0,0,0,0};
    int jb = sgC * 64;
    #pragma unroll
    for (int jj = 0; jj < 8; jj++){
      int j = jb + jj;
      float a0 = a_s[0][j], a1 = a_s[1][j];
      float4 h = hpre[jj];
      FMA4(c0, a0, h) FMA4(c1, a1, h)
    }
    #pragma unroll 8
    for (int jj = 8; jj < 64; jj++){
      int j = jb + jj;
      float a0 = a_s[0][j], a1 = a_s[1][j];
      float4 h = H4[j * 64 + qC];
      FMA4(c0, a0, h) FMA4(c1, a1, h)
    }
    parts[sgC * 64 + qC]       = c0;
    parts[512 + sgC * 64 + qC] = c1;
  }
  __syncthreads();
  if (tid < 128){
    int rr = tid >> 6, qq = tid & 63;
    float4 p[8];
    #pragma unroll
    for (int s8 = 0; s8 < 8; s8++) p[s8] = parts[rr * 512 + s8 * 64 + qq];
    float4 o;
    o.x = ((p[0].x + p[1].x) + (p[2].x + p[3].x)) + ((p[4].x + p[5].x) + (p[6].x + p[7].x));
    o.y = ((p[0].y + p[1].y) + (p[2].y + p[3].y)) + ((p[4].y + p[5].y) + (p[6].y + p[7].y));
    o.z = ((p[0].z + p[1].z) + (p[2].z + p[3].z)) + ((p[4].z + p[5].z) + (p[6].z + p[7].z));
    o.w = ((p[0].w + p[1].w) + (p[2].w + p[3].w)) + ((p[4].w + p[5].w) + (p[6].w + p[7].w));
    ((float4*)(HnOut + (i0 + rr) * DD))[qq] = o;
    if (!LAST){
      ((float4*)hn_s[rr])[qq] = o;
      double s = (double)o.x * o.x + (double)o.y * o.y
               + (double)o.z * o.z + (double)o.w * o.w;
      #pragma unroll
      for (int off = 32; off > 0; off >>= 1) s += __shfl_down(s, off);
      if (qq == 0) hnorm2[rr] = s;
    }
  }
  if (LAST) return;
  __syncthreads();

  // ---- Tail: next-layer mobius_matvec via W1T (coalesced stream) ----
  {
    int ks2 = tid >> 6, dq = tid & 63;  // 8 k-segs of 32, output dim-quad
    const float4* WT4b = (const float4*)WT2;       // [k*64 + dq]
    const float* h0 = hn_s[0]; const float* h1 = hn_s[1];
    float4 p0 = {0,0,0,0}, p1 = {0,0,0,0};
    int k0 = ks2 * 32;
    #pragma unroll 8
    for (int kk = 0; kk < 32; kk++){
      int k = k0 + kk;
      float4 wv = WT4b[k * 64 + dq];
      float a0v = h0[k], a1v = h1[k];   // wave-uniform -> LDS broadcast
      FMA4(p0, a0v, wv) FMA4(p1, a1v, wv)
    }
    parts[(ks2 * 64 + dq) * 2 + 0] = p0;
    parts[(ks2 * 64 + dq) * 2 + 1] = p1;
  }
  __syncthreads();
  {
    int rr = tid >> 8, d = tid & 255;   // waves 0-3: row 0, waves 4-7: row 1
    const float* pf2 = (const float*)parts;        // seg stride = 512 floats
    int base = ((d >> 2) * 2 + rr) * 4 + (d & 3);
    float q0 = pf2[base]        + pf2[base + 512];
    float q1 = pf2[base + 1024] + pf2[base + 1536];
    float q2 = pf2[base + 2048] + pf2[base + 2560];
    float q3 = pf2[base + 3072] + pf2[base + 3584];
    float mx = (q0 + q1) + (q2 + q3);
    double m2 = (double)mx * (double)mx;
    m2 = wred_sum(m2);
    int w2 = tid >> 6, lane2 = tid & 63;
    if (lane2 == 0) ssum[w2] = m2;
    __syncthreads();
    int b4 = rr * 4;
    double m2sum = (ssum[b4] + ssum[b4 + 1]) + (ssum[b4 + 2] + ssum[b4 + 3]);
    double mn = sqrt(m2sum); if (mn < 1e-15) mn = 1e-15;
    double xn = sqrt(hnorm2[rr]); if (xn < 1e-15) xn = 1e-15;
    double th = tanh(mn / xn * artanh_clip(xn));
    float wv = (float)((double)mx * (th / mn));
    int irow = i0 + rr;
    xs[rr * DD + d] = wv;               // next stage's Wh rows stay in LDS
    WhTn[d * NN + irow] = wv;
    if (d == 0) r2n[irow] = th * th;
  }
}

// ---------- mega kernel: stage0 (expmap+matvec0) | sync | fused L0 | sync | fused L1 ----------
__global__ __launch_bounds__(512) void mega_k(
    const float* __restrict__ Hin, const float* __restrict__ W,
    const int* __restrict__ A,
    float* __restrict__ Hf, float* __restrict__ Hn,
    float* __restrict__ WhT, float* __restrict__ WhTb,
    float* __restrict__ W1T, double* __restrict__ r2, double* __restrict__ r2b,
    float* __restrict__ out)
{
  cg::grid_group grid = cg::this_grid();
  int b = blockIdx.x, tid = threadIdx.x;
  int i0 = 2 * b;
  __shared__ float xs[2 * DD];
  __shared__ float a_s[2][NN];
  __shared__ float4 parts[1024];        // 16KB; stage0 reuses as transpose tile
  __shared__ double ssum[8];
  __shared__ float hn_s[2][DD];
  __shared__ double hnorm2[2];

  // ---- stage 0: expmap + mobius_matvec layer 0 (1 row-elem per thread) ----
  {
    int r = tid >> 8, t = tid & 255, lane = tid & 63, w = tid >> 6;
    int irow = i0 + r;
    float u = Hin[irow * DD + t];
    double p = (double)u * (double)u;
    p = wred_sum(p);
    if (lane == 0) ssum[w] = p;
    __syncthreads();
    int b4 = r * 4;
    double n2 = (ssum[b4] + ssum[b4 + 1]) + (ssum[b4 + 2] + ssum[b4 + 3]);
    double n = sqrt(n2); if (n < 1e-15) n = 1e-15;
    double tn = tanh(n);
    float h = (float)(tn / n * (double)u);
    Hf[irow * DD + t] = h;
    xs[r * DD + t] = h;
    double xn = tn < 1e-15 ? 1e-15 : tn;     // ||expmap0(u)|| = tanh(||u||)
    __syncthreads();
    // Mx[r][t] = sum_k h[r][k] * W[t][k]  (W row t L1-shared by both rows)
    const float4* Wt = (const float4*)(W + t * DD);
    const float4* hr = (const float4*)(xs + r * DD);
    float4 acc = {0,0,0,0};
    #pragma unroll 8
    for (int k = 0; k < DD / 4; k++){
      float4 wv = Wt[k], x = hr[k];
      acc.x = fmaf(x.x, wv.x, acc.x); acc.y = fmaf(x.y, wv.y, acc.y);
      acc.z = fmaf(x.z, wv.z, acc.z); acc.w = fmaf(x.w, wv.w, acc.w);
    }
    float mx = (acc.x + acc.y) + (acc.z + acc.w);
    double m2 = (double)mx * (double)mx;
    m2 = wred_sum(m2);
    if (lane == 0) ssum[w] = m2;
    __syncthreads();
    double mxn2 = (ssum[b4] + ssum[b4 + 1]) + (ssum[b4 + 2] + ssum[b4 + 3]);
    double mn = sqrt(mxn2); if (mn < 1e-15) mn = 1e-15;
    double th = tanh(mn / xn * artanh_clip(xn));
    float wv = (float)((double)mx * (th / mn));
    WhT[t * NN + irow] = wv;
    xs[r * DD + t] = wv;                // stage1's Wh rows, kept in LDS
    if (t == 0) r2[irow] = th * th;
  }
  // ---- W1 transpose: blocks 0..15, XOR-swizzled tile in parts ----
  if (b < 16){
    float* tf = (float*)parts;
    const float* W1 = W + DD * DD;
    int tr = b >> 2, tc = b & 3;
    int tx = tid & 63, ty = tid >> 6;        // 8 rows per pass
    #pragma unroll
    for (int yy = 0; yy < 64; yy += 8){
      int y = yy + ty;
      tf[y * 64 + (tx ^ y)] = W1[(tr * 64 + y) * DD + tc * 64 + tx];
    }
    __syncthreads();
    #pragma unroll
    for (int yy = 0; yy < 64; yy += 8){
      int y = yy + ty;
      W1T[(tc * 64 + y) * DD + tr * 64 + tx] = tf[tx * 64 + (y ^ tx)];
    }
  }
  grid.sync();

  // ---- stage 1: fused layer 0 (+ layer-1 matvec tail) ----
  fused_body<false>(b, tid, WhT, r2, A, Hf, W1T, Hn, WhTb, r2b,
                    xs, a_s, parts, ssum, hn_s, hnorm2);
  grid.sync();

  // ---- stage 2: fused layer 1 -> out ----
  fused_body<true>(b, tid, WhTb, r2b, A, Hn, nullptr, out, nullptr, nullptr,
                   xs, a_s, parts, ssum, hn_s, hnorm2);
}

extern "C" void kernel_launch(void* const* d_in, const int* in_sizes, int n_in,
                              void* d_out, int out_size, void* d_ws, size_t ws_size,
                              hipStream_t stream){
  const float* H_euc = (const float*)d_in[0];
  const float* W     = (const float*)d_in[1];
  const int*   A     = (const int*)d_in[2];
  float* out = (float*)d_out;

  float* Hf   = (float*)d_ws;              // N*D
  float* Hn   = Hf   + NN * DD;            // N*D
  float* WhT  = Hn   + NN * DD;            // D*N
  float* WhTb = WhT  + NN * DD;            // D*N
  float* W1T  = WhTb + NN * DD;            // D*D (transposed layer-1 W)
  double* r2  = (double*)(W1T + DD * DD);  // N
  double* r2b = r2 + NN;                   // N

  void* args[] = {
    (void*)&H_euc, (void*)&W, (void*)&A,
    (void*)&Hf, (void*)&Hn, (void*)&WhT, (void*)&WhTb,
    (void*)&W1T, (void*)&r2, (void*)&r2b, (void*)&out
  };
  hipLaunchCooperativeKernel((void*)mega_k, dim3(NN / 2), dim3(512),
                             args, 0, stream);
}

// Round 11
// 52.710 us; speedup vs baseline: 2.6339x; 2.6339x over previous
//
#include <hip/hip_runtime.h>
#include <math.h>

#define NN 512
#define DD 256

#define FMA4(P, S, V) \
  P.x = fmaf(S, (V).x, P.x); P.y = fmaf(S, (V).y, P.y); \
  P.z = fmaf(S, (V).z, P.z); P.w = fmaf(S, (V).w, P.w);

// ---------- dual-channel f64 block reduction (256 threads = 4 waves) ----------
__device__ __forceinline__ void wred_sum2(double& a, double& b){
  #pragma unroll
  for (int o = 32; o > 0; o >>= 1){
    a += __shfl_down(a, o);
    b += __shfl_down(b, o);
  }
}
__device__ void bred_sum2(double& a, double& b){
  __shared__ double sa[4], sb[4]; __shared__ double ra, rb;
  int lane = threadIdx.x & 63, w = threadIdx.x >> 6;
  wred_sum2(a, b);
  __syncthreads();
  if (lane == 0){ sa[w] = a; sb[w] = b; }
  __syncthreads();
  if (threadIdx.x == 0){
    ra = (sa[0] + sa[1]) + (sa[2] + sa[3]);
    rb = (sb[0] + sb[1]) + (sb[2] + sb[3]);
  }
  __syncthreads();
  a = ra; b = rb;
}

__device__ __forceinline__ double artanh_clip(double x){
  const double lim = 1.0 - 1e-5;           // BALL_EPS
  if (x >  lim) x =  lim;
  if (x < -lim) x = -lim;
  return 0.5 * log((1.0 + x) / (1.0 - x));
}

// ---------- K0: expmap + mobius_matvec layer 0 (2 rows/block) ----------
// Blocks 0..15 additionally produce W1T (tiled LDS transpose of layer-1 W)
// for the coalesced tail-matvec inside fused_k<false>.
__global__ __launch_bounds__(256) void matvec0_k(
    const float* __restrict__ Hin, const float* __restrict__ W,
    const float* __restrict__ W1, float* __restrict__ W1T,
    float* __restrict__ Hf, float* __restrict__ Wh, float* __restrict__ WhT,
    double* __restrict__ r2){
  __shared__ float h0s[DD], h1s[DD];
  __shared__ float tile[64][65];
  int b = blockIdx.x, t = threadIdx.x;
  int i0 = 2 * b, i1 = i0 + 1;
  float u0 = Hin[i0 * DD + t], u1 = Hin[i1 * DD + t];
  double n0 = (double)u0 * (double)u0, n1 = (double)u1 * (double)u1;
  bred_sum2(n0, n1);
  n0 = sqrt(n0); if (n0 < 1e-15) n0 = 1e-15;
  n1 = sqrt(n1); if (n1 < 1e-15) n1 = 1e-15;
  double t0 = tanh(n0), t1 = tanh(n1);
  float h0 = (float)(t0 / n0 * (double)u0);
  float h1 = (float)(t1 / n1 * (double)u1);
  Hf[i0 * DD + t] = h0; Hf[i1 * DD + t] = h1;
  double xn0 = t0 < 1e-15 ? 1e-15 : t0;    // ||expmap0(u)|| = tanh(||u||)
  double xn1 = t1 < 1e-15 ? 1e-15 : t1;
  h0s[t] = h0; h1s[t] = h1;
  __syncthreads();
  const float4* Wt = (const float4*)(W + t * DD);   // Mx[t] = sum_k H[k]*W[t][k]
  const float4* r0 = (const float4*)h0s;
  const float4* r1 = (const float4*)h1s;
  float4 A0 = {0,0,0,0}, A1 = {0,0,0,0};
  #pragma unroll 8
  for (int k = 0; k < DD / 4; k++){
    float4 w = Wt[k], x0 = r0[k], x1 = r1[k];
    A0.x = fmaf(x0.x, w.x, A0.x); A0.y = fmaf(x0.y, w.y, A0.y);
    A0.z = fmaf(x0.z, w.z, A0.z); A0.w = fmaf(x0.w, w.w, A0.w);
    A1.x = fmaf(x1.x, w.x, A1.x); A1.y = fmaf(x1.y, w.y, A1.y);
    A1.z = fmaf(x1.z, w.z, A1.z); A1.w = fmaf(x1.w, w.w, A1.w);
  }
  float mx0 = (A0.x + A0.y) + (A0.z + A0.w);
  float mx1 = (A1.x + A1.y) + (A1.z + A1.w);
  double m0 = (double)mx0 * (double)mx0, m1 = (double)mx1 * (double)mx1;
  bred_sum2(m0, m1);
  double mn0 = sqrt(m0); if (mn0 < 1e-15) mn0 = 1e-15;
  double mn1 = sqrt(m1); if (mn1 < 1e-15) mn1 = 1e-15;
  double th0 = tanh(mn0 / xn0 * artanh_clip(xn0));
  double th1 = tanh(mn1 / xn1 * artanh_clip(xn1));
  float w0 = (float)((double)mx0 * (th0 / mn0));
  float w1 = (float)((double)mx1 * (th1 / mn1));
  Wh[i0 * DD + t] = w0;  Wh[i1 * DD + t] = w1;
  WhT[t * NN + i0] = w0; WhT[t * NN + i1] = w1;
  if (t == 0){ r2[i0] = th0 * th0; r2[i1] = th1 * th1; }

  // ---- W1 transpose: blocks 0..15 each do one 64x64 tile (block-uniform branch) ----
  if (b < 16){
    int tr = b >> 2, tc = b & 3;
    int tx = t & 63, ty4 = t >> 6;           // 4 rows per pass
    #pragma unroll
    for (int yy = 0; yy < 64; yy += 4)
      tile[yy + ty4][tx] = W1[(tr * 64 + yy + ty4) * DD + tc * 64 + tx];
    __syncthreads();
    #pragma unroll
    for (int yy = 0; yy < 64; yy += 4)
      W1T[(tc * 64 + yy + ty4) * DD + tr * 64 + tx] = tile[tx][yy + ty4];
  }
}

// ---------- fused: Gram + score(f64) + softmax + att@H (+ layer-1 matvec tail) ----------
// R4-proven 52.9µs configuration: 256 blocks x 512 threads, hpre[8].
template<bool LAST>
__global__ __launch_bounds__(512) void fused_k(
    const float* __restrict__ Wh, const float* __restrict__ WhT,
    const double* __restrict__ r2, const int* __restrict__ A,
    const float* __restrict__ H, const float* __restrict__ WT2,
    float* __restrict__ Hn, float* __restrict__ Whn,
    float* __restrict__ WhTn, double* __restrict__ r2n){
  int b = blockIdx.x, tid = threadIdx.x;
  int i0 = 2 * b;
  __shared__ float xs[2 * DD];
  __shared__ float a_s[2][NN];
  __shared__ float4 parts[1024];        // 16KB, reused by phases A-combine, C, tail
  __shared__ double ssum[8];
  __shared__ float hn_s[2][DD];
  __shared__ double hnorm2[2];

  xs[tid] = Wh[i0 * DD + tid];
  __syncthreads();

  // ---- Phase A: Gram partials (coalesced WhT stream) ----
  {
    int ks = tid >> 7, jq = tid & 127;  // 4 k-segs of 64 dims, column-quad
    const float4* WT4 = (const float4*)WhT;        // [k*128 + jq]
    const float4* x04 = (const float4*)xs;
    const float4* x14 = (const float4*)(xs + DD);
    float4 p0 = {0,0,0,0}, p1 = {0,0,0,0};
    int kq0 = ks * 16;
    #pragma unroll 4
    for (int kk = 0; kk < 16; kk++){
      float4 xa = x04[kq0 + kk], xb = x14[kq0 + kk];
      const float4* wp = WT4 + (kq0 + kk) * 4 * 128 + jq;
      float4 wa = wp[0], wb = wp[128], wc = wp[256], wd = wp[384];
      FMA4(p0, xa.x, wa) FMA4(p0, xa.y, wb) FMA4(p0, xa.z, wc) FMA4(p0, xa.w, wd)
      FMA4(p1, xb.x, wa) FMA4(p1, xb.y, wb) FMA4(p1, xb.z, wc) FMA4(p1, xb.w, wd)
    }
    parts[(ks * 128 + jq) * 2 + 0] = p0;
    parts[(ks * 128 + jq) * 2 + 1] = p1;
  }
  __syncthreads();

  // ---- Phase C prefetch: first 8 rows of this thread's j-segment (hides under B) ----
  int sgC = tid >> 6, qC = tid & 63;
  const float4* H4 = (const float4*)H;
  float4 hpre[8];
  #pragma unroll
  for (int jj = 0; jj < 8; jj++) hpre[jj] = H4[(sgC * 64 + jj) * 64 + qC];

  // ---- Phase B: scores + fixed-shift softmax ----
  int r = tid >> 8, j2 = tid & 255;     // waves 0-3: row i0, waves 4-7: row i1
  int i = i0 + r;
  double X2 = r2[i];
  const float* pf = (const float*)parts;          // ks stride = 1024 floats
  auto dsum = [&](int j) -> double {
    int base = (((j >> 2) * 2 + r) << 2) + (j & 3);
    return ((double)pf[base] + (double)pf[base + 1024])
         + ((double)pf[base + 2048] + (double)pf[base + 3072]);
  };
  double d0 = dsum(j2), d1 = dsum(j2 + 256);

  auto score = [&](double dot, double Y2, int jj) -> double {
    if (i == jj) return 0.0;            // exact: mobius_add(-x,x)=0
    double xy = -dot;
    double a  = 1.0 + 2.0 * xy + Y2;
    double bb = 1.0 - X2;
    double den = 1.0 + 2.0 * xy + X2 * Y2;
    if (den < 1e-15) den = 1e-15;
    double nn = a * a * X2 + 2.0 * a * bb * xy + bb * bb * Y2;
    if (nn < 0.0) nn = 0.0;
    double s = sqrt(nn);
    double smax = den * (1.0 - 1e-5);   // artanh arg clip at 1-1e-5
    if (s > smax) s = smax;
    double d = log((den + s) / (den - s)); // = 2*artanh(s/den), one div
    return d * d;
  };

  double Y0 = r2[j2], Y1 = r2[j2 + 256];
  int m0 = A[i * NN + j2], m1 = A[i * NN + j2 + 256];
  double e0 = 0.0, e1 = 0.0;
  if (m0) e0 = exp(score(d0, Y0, j2) - 150.0);       // scores in [0,150)
  if (m1) e1 = exp(score(d1, Y1, j2 + 256) - 150.0);

  double part = e0 + e1;
  #pragma unroll
  for (int o = 32; o > 0; o >>= 1) part += __shfl_down(part, o);
  int w = tid >> 6, lane = tid & 63;
  if (lane == 0) ssum[w] = part;
  __syncthreads();
  int base4 = r * 4;
  double sum = (ssum[base4] + ssum[base4 + 1]) + (ssum[base4 + 2] + ssum[base4 + 3]);
  double inv = 1.0 / sum;
  a_s[r][j2]       = m0 ? (float)(e0 * inv) : 0.f;
  a_s[r][j2 + 256] = m1 ? (float)(e1 * inv) : 0.f;
  __syncthreads();

  // ---- Phase C: att @ H, 8-way j-split; 8 prefetched + 56 streamed rows ----
  {
    float4 c0 = {0,0,0,0}, c1 = {0,0,0,0};
    int jb = sgC * 64;
    #pragma unroll
    for (int jj = 0; jj < 8; jj++){
      int j = jb + jj;
      float a0 = a_s[0][j], a1 = a_s[1][j];
      float4 h = hpre[jj];
      FMA4(c0, a0, h) FMA4(c1, a1, h)
    }
    #pragma unroll 8
    for (int jj = 8; jj < 64; jj++){
      int j = jb + jj;
      float a0 = a_s[0][j], a1 = a_s[1][j];
      float4 h = H4[j * 64 + qC];
      FMA4(c0, a0, h) FMA4(c1, a1, h)
    }
    parts[sgC * 64 + qC]       = c0;
    parts[512 + sgC * 64 + qC] = c1;
  }
  __syncthreads();
  if (tid < 128){
    int rr = tid >> 6, qq = tid & 63;
    float4 p[8];
    #pragma unroll
    for (int s8 = 0; s8 < 8; s8++) p[s8] = parts[rr * 512 + s8 * 64 + qq];
    float4 o;
    o.x = ((p[0].x + p[1].x) + (p[2].x + p[3].x)) + ((p[4].x + p[5].x) + (p[6].x + p[7].x));
    o.y = ((p[0].y + p[1].y) + (p[2].y + p[3].y)) + ((p[4].y + p[5].y) + (p[6].y + p[7].y));
    o.z = ((p[0].z + p[1].z) + (p[2].z + p[3].z)) + ((p[4].z + p[5].z) + (p[6].z + p[7].z));
    o.w = ((p[0].w + p[1].w) + (p[2].w + p[3].w)) + ((p[4].w + p[5].w) + (p[6].w + p[7].w));
    ((float4*)(Hn + (i0 + rr) * DD))[qq] = o;
    if (!LAST){
      ((float4*)hn_s[rr])[qq] = o;
      double s = (double)o.x * o.x + (double)o.y * o.y
               + (double)o.z * o.z + (double)o.w * o.w;
      #pragma unroll
      for (int off = 32; off > 0; off >>= 1) s += __shfl_down(s, off);
      if (qq == 0) hnorm2[rr] = s;
    }
  }
  if (LAST) return;
  __syncthreads();

  // ---- Tail: layer-1 mobius_matvec via W1T (coalesced stream) ----
  {
    int ks2 = tid >> 6, dq = tid & 63;  // 8 k-segs of 32, output dim-quad
    const float4* WT4b = (const float4*)WT2;       // [k*64 + dq]
    const float* h0 = hn_s[0]; const float* h1 = hn_s[1];
    float4 p0 = {0,0,0,0}, p1 = {0,0,0,0};
    int k0 = ks2 * 32;
    #pragma unroll 8
    for (int kk = 0; kk < 32; kk++){
      int k = k0 + kk;
      float4 wv = WT4b[k * 64 + dq];
      float a0v = h0[k], a1v = h1[k];   // wave-uniform -> LDS broadcast
      FMA4(p0, a0v, wv) FMA4(p1, a1v, wv)
    }
    parts[(ks2 * 64 + dq) * 2 + 0] = p0;
    parts[(ks2 * 64 + dq) * 2 + 1] = p1;
  }
  __syncthreads();
  {
    int rr = tid >> 8, d = tid & 255;   // waves 0-3: row 0, waves 4-7: row 1
    const float* pf2 = (const float*)parts;        // seg stride = 512 floats
    int base = ((d >> 2) * 2 + rr) * 4 + (d & 3);
    float q0 = pf2[base]        + pf2[base + 512];
    float q1 = pf2[base + 1024] + pf2[base + 1536];
    float q2 = pf2[base + 2048] + pf2[base + 2560];
    float q3 = pf2[base + 3072] + pf2[base + 3584];
    float mx = (q0 + q1) + (q2 + q3);
    double m2 = (double)mx * (double)mx;
    #pragma unroll
    for (int o = 32; o > 0; o >>= 1) m2 += __shfl_down(m2, o);
    int w2 = tid >> 6, lane2 = tid & 63;
    if (lane2 == 0) ssum[w2] = m2;
    __syncthreads();
    int b4 = rr * 4;
    double m2sum = (ssum[b4] + ssum[b4 + 1]) + (ssum[b4 + 2] + ssum[b4 + 3]);
    double mn = sqrt(m2sum); if (mn < 1e-15) mn = 1e-15;
    double xn = sqrt(hnorm2[rr]); if (xn < 1e-15) xn = 1e-15;
    double th = tanh(mn / xn * artanh_clip(xn));
    float wv = (float)((double)mx * (th / mn));
    int irow = i0 + rr;
    Whn[irow * DD + d] = wv;
    WhTn[d * NN + irow] = wv;
    if (d == 0) r2n[irow] = th * th;
  }
}

extern "C" void kernel_launch(void* const* d_in, const int* in_sizes, int n_in,
                              void* d_out, int out_size, void* d_ws, size_t ws_size,
                              hipStream_t stream){
  const float* H_euc = (const float*)d_in[0];
  const float* W     = (const float*)d_in[1];
  const int*   A     = (const int*)d_in[2];
  float* out = (float*)d_out;

  float* Hf   = (float*)d_ws;              // N*D
  float* Hn   = Hf   + NN * DD;            // N*D
  float* Wh   = Hn   + NN * DD;            // N*D
  float* WhT  = Wh   + NN * DD;            // D*N
  float* Whb  = WhT  + NN * DD;            // N*D (layer-1 Wh)
  float* WhTb = Whb  + NN * DD;            // D*N
  float* W1T  = WhTb + NN * DD;            // D*D (transposed layer-1 W)
  double* r2  = (double*)(W1T + DD * DD);  // N
  double* r2b = r2 + NN;                   // N

  matvec0_k<<<NN / 2, DD, 0, stream>>>(H_euc, W, W + DD * DD, W1T, Hf, Wh, WhT, r2);
  fused_k<false><<<NN / 2, 2 * DD, 0, stream>>>(Wh, WhT, r2, A, Hf, W1T, Hn, Whb, WhTb, r2b);
  fused_k<true> <<<NN / 2, 2 * DD, 0, stream>>>(Whb, WhTb, r2b, A, Hn, nullptr, out, nullptr, nullptr, nullptr);
}